// Round 5
// baseline (171.719 us; speedup 1.0000x reference)
//
#include <hip/hip_runtime.h>

#define NUM_NODES 100000
#define NUM_EDGES 400000
#define F_IN 16
#define F_EDGE 8
#define EMB 16
#define NUM_GRAPHS 256

#define NT (NUM_EDGES / 8)   // 50000 8-edge tiles
#define EDGE_GRID 2048

#define NPB 128                                        // nodes per node_kernel block
#define NODE_BLOCKS ((NUM_NODES + NPB - 1) / NPB)      // 782

// workspace floats to zero: sums + cnt + gmax + gsum + gcnt (contiguous)
#define WS_ZERO_FLOATS (NUM_NODES * EMB + NUM_NODES + 2 * NUM_GRAPHS * EMB + NUM_GRAPHS)

// ---------------------------------------------------------------------------
// Zero the accumulator workspace (replaces hipMemsetAsync — probe: is the
// memset-in-graph the hidden ~90 µs?). WS_ZERO_FLOATS = 1,708,448, /4 exact.
// ---------------------------------------------------------------------------
__global__ __launch_bounds__(256) void zero_kernel(float4* __restrict__ ws)
{
    const int n4 = WS_ZERO_FLOATS / 4;     // 427,112 float4s
    const int stride = gridDim.x * 256;
    for (int i = blockIdx.x * 256 + threadIdx.x; i < n4; i += stride)
        ws[i] = make_float4(0.f, 0.f, 0.f, 0.f);
}

// ---------------------------------------------------------------------------
// Edge kernel: weights live in REGISTERS (no LDS, no barriers).
// Thread = (o = tid&15, ih = bit4, eL = tid>>5): 8 edges per block-iteration,
// each edge's 16 i-rows split across the 2 ih-halves (64+8 regs of W/bias per
// thread), combined with one __shfl_xor across lanes differing in bit4.
// Manual 1-deep prefetch pipeline hides ea/x latency under the 80-FMA body.
// ---------------------------------------------------------------------------
__global__ __launch_bounds__(256, 3) void edge_kernel(
    const float* __restrict__ x, const int* __restrict__ ei,
    const float* __restrict__ ea, const float* __restrict__ nn1_w,
    const float* __restrict__ nn1_b, float* __restrict__ sums,
    float* __restrict__ cnt)
{
    const int tid = threadIdx.x;
    const int o   = tid & 15;
    const int ih  = (tid >> 4) & 1;
    const int eL  = tid >> 5;              // 0..7

    // per-thread weight rows r = (ih*8+ii)*16 + o  (same addrs across eL ->
    // cache broadcast; one-time cost)
    float4 w0[8], w1[8];
    float  br[8];
    #pragma unroll
    for (int ii = 0; ii < 8; ii++) {
        const int r = (ih * 8 + ii) * 16 + o;
        w0[ii] = *(const float4*)&nn1_w[r * 8];
        w1[ii] = *(const float4*)&nn1_w[r * 8 + 4];
        br[ii] = nn1_b[r];
    }

    int t = blockIdx.x;                    // grid-stride over 50000 tiles
    int e   = t * 8 + eL;
    int src = ei[e];
    int dst = ei[NUM_EDGES + e];
    float4 a0 = *(const float4*)&ea[e * 8];
    float4 a1 = *(const float4*)&ea[e * 8 + 4];
    float4 x0 = *(const float4*)&x[src * 16 + ih * 8];
    float4 x1 = *(const float4*)&x[src * 16 + ih * 8 + 4];

    while (true) {
        const int tn = t + EDGE_GRID;
        const bool more = (tn < NT);
        int srcn = 0, dstn = 0;
        float4 na0, na1, nx0, nx1;
        if (more) {                         // prefetch next tile's operands
            const int en = tn * 8 + eL;
            srcn = ei[en];
            dstn = ei[NUM_EDGES + en];
            na0 = *(const float4*)&ea[en * 8];
            na1 = *(const float4*)&ea[en * 8 + 4];
            nx0 = *(const float4*)&x[srcn * 16 + ih * 8];
            nx1 = *(const float4*)&x[srcn * 16 + ih * 8 + 4];
        }

        // compute current tile: 8 i-rows x (8-FMA dot + ReLU + acc FMA)
        const float xr[8] = {x0.x, x0.y, x0.z, x0.w, x1.x, x1.y, x1.z, x1.w};
        float acc = 0.f;
        #pragma unroll
        for (int ii = 0; ii < 8; ii++) {
            float u = br[ii];
            u = fmaf(a0.x, w0[ii].x, u); u = fmaf(a0.y, w0[ii].y, u);
            u = fmaf(a0.z, w0[ii].z, u); u = fmaf(a0.w, w0[ii].w, u);
            u = fmaf(a1.x, w1[ii].x, u); u = fmaf(a1.y, w1[ii].y, u);
            u = fmaf(a1.z, w1[ii].z, u); u = fmaf(a1.w, w1[ii].w, u);
            acc = fmaf(xr[ii], fmaxf(u, 0.f), acc);
        }
        acc += __shfl_xor(acc, 16);         // combine ih halves (lane bit4)

        if (ih == 0)         atomicAdd(&sums[dst * 16 + o], acc);
        if ((tid & 31) == 0) atomicAdd(&cnt[dst], 1.f);   // one lane per edge

        if (!more) break;
        t = tn; src = srcn; dst = dstn;
        a0 = na0; a1 = na1; x0 = nx0; x1 = nx1;
    }
}

// ---------------------------------------------------------------------------
// Node kernel (unchanged from R4, absmax 0): one block per 128 nodes; h =
// relu(agg + x@root_w^T + conv_b); 16 flusher threads carry per-channel
// (max,sum,count) register accumulators, flushing atomics only on graph
// boundary / block end.
// ---------------------------------------------------------------------------
__global__ __launch_bounds__(256) void node_kernel(
    const float* __restrict__ x, const int* __restrict__ batch,
    const float* __restrict__ root_w, const float* __restrict__ conv_b,
    const float* __restrict__ sums, const float* __restrict__ cnt,
    unsigned int* __restrict__ gmax, float* __restrict__ gsum,
    float* __restrict__ gcnt)
{
    __shared__ float rwT[256];   // rwT[i*16+o] = root_w[o*16+i]
    __shared__ float xsh[256];
    __shared__ float ssh[256];
    __shared__ float csh[16];
    __shared__ int   bsh[16];
    __shared__ float hsh[256];

    const int tid = threadIdx.x;
    const int j   = tid >> 4;
    const int o   = tid & 15;
    const int n0  = blockIdx.x * NPB;

    rwT[(tid & 15) * 16 + (tid >> 4)] = root_w[tid];
    const float cb = conv_b[o];

    int   curg = batch[n0];
    float am = 0.f, asum = 0.f, ac = 0.f;

    for (int s0 = 0; s0 < NPB; s0 += 16) {
        const int base = n0 + s0;
        const int idx  = base * 16 + tid;
        const bool v   = (idx < NUM_NODES * 16);
        const float xv = v ? x[idx]    : 0.f;
        const float sv = v ? sums[idx] : 0.f;
        float cv = 1.f; int bv = -1;
        if (tid < 16) {
            const int n = base + tid;
            if (n < NUM_NODES) { cv = cnt[n]; bv = batch[n]; }
        }
        __syncthreads();   // prev sub-tile's hsh/bsh fully consumed
        xsh[tid] = xv; ssh[tid] = sv;
        if (tid < 16) { csh[tid] = cv; bsh[tid] = bv; }
        __syncthreads();

        float a = cb + ssh[j * 16 + o] / fmaxf(csh[j], 1.f);
        #pragma unroll
        for (int i = 0; i < F_IN; i++)
            a = fmaf(xsh[j * 16 + i], rwT[i * 16 + o], a);
        hsh[tid] = fmaxf(a, 0.f);
        __syncthreads();   // hsh ready

        if (tid < 16) {
            #pragma unroll 1
            for (int jj = 0; jj < 16; jj++) {
                const int g = bsh[jj];
                if (g < 0) break;
                if (g != curg) {
                    atomicMax(&gmax[curg * 16 + o], __float_as_uint(am));
                    atomicAdd(&gsum[curg * 16 + o], asum);
                    if (o == 0) atomicAdd(&gcnt[curg], ac);
                    am = 0.f; asum = 0.f; ac = 0.f; curg = g;
                }
                const float h = hsh[jj * 16 + o];
                am = fmaxf(am, h); asum += h; ac += 1.f;
            }
        }
    }

    if (tid < 16) {
        atomicMax(&gmax[curg * 16 + o], __float_as_uint(am));
        atomicAdd(&gsum[curg * 16 + o], asum);
        if (o == 0) atomicAdd(&gcnt[curg], ac);
    }
}

// Head MLP: one thread per graph, single block.
__global__ __launch_bounds__(256) void head_kernel(
    const unsigned int* __restrict__ gmax, const float* __restrict__ gsum,
    const float* __restrict__ gcnt,
    const float* __restrict__ lin1_w, const float* __restrict__ lin1_b,
    const float* __restrict__ lin2_w, const float* __restrict__ lin2_b,
    float* __restrict__ out)
{
    const int g = threadIdx.x;

    float pooled[2 * EMB];
    #pragma unroll
    for (int o = 0; o < EMB; o++) pooled[o] = __uint_as_float(gmax[g * 16 + o]);
    const float c = fmaxf(gcnt[g], 1.f);
    #pragma unroll
    for (int o = 0; o < EMB; o++) pooled[EMB + o] = gsum[g * 16 + o] / c;

    float acc = lin2_b[0];
    #pragma unroll
    for (int k = 0; k < EMB; k++) {
        float a = lin1_b[k];
        #pragma unroll
        for (int cc = 0; cc < 2 * EMB; cc++)
            a = fmaf(pooled[cc], lin1_w[k * 32 + cc], a);
        acc = fmaf(fmaxf(a, 0.f), lin2_w[k], acc);
    }
    out[g] = acc;
}

extern "C" void kernel_launch(void* const* d_in, const int* in_sizes, int n_in,
                              void* d_out, int out_size, void* d_ws, size_t ws_size,
                              hipStream_t stream) {
    const float* x      = (const float*)d_in[0];
    const int*   ei     = (const int*)d_in[1];
    const float* ea     = (const float*)d_in[2];
    const int*   batch  = (const int*)d_in[3];
    const float* nn1_w  = (const float*)d_in[4];
    const float* nn1_b  = (const float*)d_in[5];
    const float* root_w = (const float*)d_in[6];
    const float* conv_b = (const float*)d_in[7];
    const float* lin1_w = (const float*)d_in[8];
    const float* lin1_b = (const float*)d_in[9];
    const float* lin2_w = (const float*)d_in[10];
    const float* lin2_b = (const float*)d_in[11];
    float* out = (float*)d_out;

    float*        sums = (float*)d_ws;
    float*        cnt  = sums + (size_t)NUM_NODES * EMB;
    unsigned int* gmax = (unsigned int*)(cnt + NUM_NODES);
    float*        gsum = (float*)(gmax + NUM_GRAPHS * EMB);
    float*        gcnt = gsum + NUM_GRAPHS * EMB;

    zero_kernel<<<1024, 256, 0, stream>>>((float4*)d_ws);
    edge_kernel<<<EDGE_GRID, 256, 0, stream>>>(x, ei, ea, nn1_w, nn1_b, sums, cnt);
    node_kernel<<<NODE_BLOCKS, 256, 0, stream>>>(
        x, batch, root_w, conv_b, sums, cnt, gmax, gsum, gcnt);
    head_kernel<<<1, 256, 0, stream>>>(gmax, gsum, gcnt,
                                       lin1_w, lin1_b, lin2_w, lin2_b, out);
}

// Round 6
// 170.891 us; speedup vs baseline: 1.0048x; 1.0048x over previous
//
#include <hip/hip_runtime.h>

#define NUM_NODES 100000
#define NUM_EDGES 400000
#define F_IN 16
#define F_EDGE 8
#define EMB 16
#define NUM_GRAPHS 256

#define EDGE_TILES 5                                   // 32-edge tiles per block
#define EDGE_BLOCKS (NUM_EDGES / (32 * EDGE_TILES))    // 2500

#define NPB 128                                        // nodes per node_kernel block
#define NODE_BLOCKS ((NUM_NODES + NPB - 1) / NPB)      // 782

// workspace floats to zero: sums + cnt + gmax + gsum + gcnt (contiguous)
#define WS_ZERO_FLOATS (NUM_NODES * EMB + NUM_NODES + 2 * NUM_GRAPHS * EMB + NUM_GRAPHS)

// ---------------------------------------------------------------------------
// Zero the accumulator workspace. WS_ZERO_FLOATS = 1,708,448, /4 exact.
// ---------------------------------------------------------------------------
__global__ __launch_bounds__(256) void zero_kernel(float4* __restrict__ ws)
{
    const int n4 = WS_ZERO_FLOATS / 4;
    const int stride = gridDim.x * 256;
    for (int i = blockIdx.x * 256 + threadIdx.x; i < n4; i += stride)
        ws[i] = make_float4(0.f, 0.f, 0.f, 0.f);
}

// ---------------------------------------------------------------------------
// Edge kernel — R4 structure (LDS weights, 2 edges/thread, barrier-free tile
// loop) MINUS the explicit prefetch pipeline: rely on wave-level TLP (target
// ~65-75 VGPR -> 6-8 waves/SIMD) instead of ILP for latency hiding.
//   wtp row stride 12: slots 0-7 = weights (bank 12o mod 32, 2-way = free),
//   slot 8 = bias (read once at start into br[]).
// ---------------------------------------------------------------------------
__global__ __launch_bounds__(256) void edge_kernel(
    const float* __restrict__ x, const int* __restrict__ ei,
    const float* __restrict__ ea, const float* __restrict__ nn1_w,
    const float* __restrict__ nn1_b, float* __restrict__ sums,
    float* __restrict__ cnt)
{
    __shared__ float wtp[256 * 12];   // row r=(i*16+o): 8 weights + bias + 3 pad

    const int tid = threadIdx.x;
    const int eL  = tid >> 4;
    const int o   = tid & 15;

    #pragma unroll
    for (int t = tid; t < F_IN * EMB * F_EDGE; t += 256)
        wtp[(t >> 3) * 12 + (t & 7)] = nn1_w[t];
    wtp[tid * 12 + 8] = nn1_b[tid];                    // row tid = i*16+o
    __syncthreads();                                   // the ONLY barrier

    float br[F_IN];
    #pragma unroll
    for (int i = 0; i < F_IN; i++) br[i] = wtp[(i * 16 + o) * 12 + 8];

    for (int t = 0; t < EDGE_TILES; t++) {
        const int e0 = (blockIdx.x * EDGE_TILES + t) * 32;
        const int eA = e0 + eL;
        const int eB = e0 + 16 + eL;

        const int srcA = ei[eA];
        const int srcB = ei[eB];
        const int dstA = ei[NUM_EDGES + eA];
        const int dstB = ei[NUM_EDGES + eB];

        const float4 a00 = *(const float4*)&ea[eA * 8];
        const float4 a01 = *(const float4*)&ea[eA * 8 + 4];
        const float4 a10 = *(const float4*)&ea[eB * 8];
        const float4 a11 = *(const float4*)&ea[eB * 8 + 4];

        float xr0[F_IN], xr1[F_IN];
        #pragma unroll
        for (int r = 0; r < 4; r++) {
            const float4 v0 = *(const float4*)&x[srcA * 16 + 4 * r];
            const float4 v1 = *(const float4*)&x[srcB * 16 + 4 * r];
            xr0[4 * r + 0] = v0.x; xr0[4 * r + 1] = v0.y;
            xr0[4 * r + 2] = v0.z; xr0[4 * r + 3] = v0.w;
            xr1[4 * r + 0] = v1.x; xr1[4 * r + 1] = v1.y;
            xr1[4 * r + 2] = v1.z; xr1[4 * r + 3] = v1.w;
        }

        float acc0 = 0.f, acc1 = 0.f;
        #pragma unroll
        for (int i = 0; i < F_IN; i++) {
            const float* wr = &wtp[(i * 16 + o) * 12];
            const float4 w0 = *(const float4*)wr;
            const float4 w1 = *(const float4*)(wr + 4);
            float u = br[i];
            u = fmaf(a00.x, w0.x, u); u = fmaf(a00.y, w0.y, u);
            u = fmaf(a00.z, w0.z, u); u = fmaf(a00.w, w0.w, u);
            u = fmaf(a01.x, w1.x, u); u = fmaf(a01.y, w1.y, u);
            u = fmaf(a01.z, w1.z, u); u = fmaf(a01.w, w1.w, u);
            acc0 = fmaf(xr0[i], fmaxf(u, 0.f), acc0);
            float v = br[i];
            v = fmaf(a10.x, w0.x, v); v = fmaf(a10.y, w0.y, v);
            v = fmaf(a10.z, w0.z, v); v = fmaf(a10.w, w0.w, v);
            v = fmaf(a11.x, w1.x, v); v = fmaf(a11.y, w1.y, v);
            v = fmaf(a11.z, w1.z, v); v = fmaf(a11.w, w1.w, v);
            acc1 = fmaf(xr1[i], fmaxf(v, 0.f), acc1);
        }

        atomicAdd(&sums[dstA * 16 + o], acc0);
        atomicAdd(&sums[dstB * 16 + o], acc1);
        if (o == 0) {
            atomicAdd(&cnt[dstA], 1.f);
            atomicAdd(&cnt[dstB], 1.f);
        }
    }
}

// ---------------------------------------------------------------------------
// Node kernel (unchanged, absmax 0): one block per 128 nodes; h = relu(agg +
// x@root_w^T + conv_b); 16 flusher threads carry per-channel (max,sum,count)
// register accumulators, flushing atomics only on graph boundary / block end.
// ---------------------------------------------------------------------------
__global__ __launch_bounds__(256) void node_kernel(
    const float* __restrict__ x, const int* __restrict__ batch,
    const float* __restrict__ root_w, const float* __restrict__ conv_b,
    const float* __restrict__ sums, const float* __restrict__ cnt,
    unsigned int* __restrict__ gmax, float* __restrict__ gsum,
    float* __restrict__ gcnt)
{
    __shared__ float rwT[256];   // rwT[i*16+o] = root_w[o*16+i]
    __shared__ float xsh[256];
    __shared__ float ssh[256];
    __shared__ float csh[16];
    __shared__ int   bsh[16];
    __shared__ float hsh[256];

    const int tid = threadIdx.x;
    const int j   = tid >> 4;
    const int o   = tid & 15;
    const int n0  = blockIdx.x * NPB;

    rwT[(tid & 15) * 16 + (tid >> 4)] = root_w[tid];
    const float cb = conv_b[o];

    int   curg = batch[n0];
    float am = 0.f, asum = 0.f, ac = 0.f;

    for (int s0 = 0; s0 < NPB; s0 += 16) {
        const int base = n0 + s0;
        const int idx  = base * 16 + tid;
        const bool v   = (idx < NUM_NODES * 16);
        const float xv = v ? x[idx]    : 0.f;
        const float sv = v ? sums[idx] : 0.f;
        float cv = 1.f; int bv = -1;
        if (tid < 16) {
            const int n = base + tid;
            if (n < NUM_NODES) { cv = cnt[n]; bv = batch[n]; }
        }
        __syncthreads();   // prev sub-tile's hsh/bsh fully consumed
        xsh[tid] = xv; ssh[tid] = sv;
        if (tid < 16) { csh[tid] = cv; bsh[tid] = bv; }
        __syncthreads();

        float a = cb + ssh[j * 16 + o] / fmaxf(csh[j], 1.f);
        #pragma unroll
        for (int i = 0; i < F_IN; i++)
            a = fmaf(xsh[j * 16 + i], rwT[i * 16 + o], a);
        hsh[tid] = fmaxf(a, 0.f);
        __syncthreads();   // hsh ready

        if (tid < 16) {
            #pragma unroll 1
            for (int jj = 0; jj < 16; jj++) {
                const int g = bsh[jj];
                if (g < 0) break;
                if (g != curg) {
                    atomicMax(&gmax[curg * 16 + o], __float_as_uint(am));
                    atomicAdd(&gsum[curg * 16 + o], asum);
                    if (o == 0) atomicAdd(&gcnt[curg], ac);
                    am = 0.f; asum = 0.f; ac = 0.f; curg = g;
                }
                const float h = hsh[jj * 16 + o];
                am = fmaxf(am, h); asum += h; ac += 1.f;
            }
        }
    }

    if (tid < 16) {
        atomicMax(&gmax[curg * 16 + o], __float_as_uint(am));
        atomicAdd(&gsum[curg * 16 + o], asum);
        if (o == 0) atomicAdd(&gcnt[curg], ac);
    }
}

// Head MLP: one thread per graph, single block.
__global__ __launch_bounds__(256) void head_kernel(
    const unsigned int* __restrict__ gmax, const float* __restrict__ gsum,
    const float* __restrict__ gcnt,
    const float* __restrict__ lin1_w, const float* __restrict__ lin1_b,
    const float* __restrict__ lin2_w, const float* __restrict__ lin2_b,
    float* __restrict__ out)
{
    const int g = threadIdx.x;

    float pooled[2 * EMB];
    #pragma unroll
    for (int o = 0; o < EMB; o++) pooled[o] = __uint_as_float(gmax[g * 16 + o]);
    const float c = fmaxf(gcnt[g], 1.f);
    #pragma unroll
    for (int o = 0; o < EMB; o++) pooled[EMB + o] = gsum[g * 16 + o] / c;

    float acc = lin2_b[0];
    #pragma unroll
    for (int k = 0; k < EMB; k++) {
        float a = lin1_b[k];
        #pragma unroll
        for (int cc = 0; cc < 2 * EMB; cc++)
            a = fmaf(pooled[cc], lin1_w[k * 32 + cc], a);
        acc = fmaf(fmaxf(a, 0.f), lin2_w[k], acc);
    }
    out[g] = acc;
}

extern "C" void kernel_launch(void* const* d_in, const int* in_sizes, int n_in,
                              void* d_out, int out_size, void* d_ws, size_t ws_size,
                              hipStream_t stream) {
    const float* x      = (const float*)d_in[0];
    const int*   ei     = (const int*)d_in[1];
    const float* ea     = (const float*)d_in[2];
    const int*   batch  = (const int*)d_in[3];
    const float* nn1_w  = (const float*)d_in[4];
    const float* nn1_b  = (const float*)d_in[5];
    const float* root_w = (const float*)d_in[6];
    const float* conv_b = (const float*)d_in[7];
    const float* lin1_w = (const float*)d_in[8];
    const float* lin1_b = (const float*)d_in[9];
    const float* lin2_w = (const float*)d_in[10];
    const float* lin2_b = (const float*)d_in[11];
    float* out = (float*)d_out;

    float*        sums = (float*)d_ws;
    float*        cnt  = sums + (size_t)NUM_NODES * EMB;
    unsigned int* gmax = (unsigned int*)(cnt + NUM_NODES);
    float*        gsum = (float*)(gmax + NUM_GRAPHS * EMB);
    float*        gcnt = gsum + NUM_GRAPHS * EMB;

    zero_kernel<<<1024, 256, 0, stream>>>((float4*)d_ws);
    edge_kernel<<<EDGE_BLOCKS, 256, 0, stream>>>(x, ei, ea, nn1_w, nn1_b, sums, cnt);
    node_kernel<<<NODE_BLOCKS, 256, 0, stream>>>(
        x, batch, root_w, conv_b, sums, cnt, gmax, gsum, gcnt);
    head_kernel<<<1, 256, 0, stream>>>(gmax, gsum, gcnt,
                                       lin1_w, lin1_b, lin2_w, lin2_b, out);
}